// Round 11
// baseline (947.206 us; speedup 1.0000x reference)
//
#include <hip/hip_runtime.h>

namespace {

constexpr int kB = 64;
constexpr int kL = 4096;
constexpr float kLrW = 1.0f / 64.0f;
constexpr float kLrF = 1.0f / 128.0f;
constexpr float kGradMax = 30.0f;
constexpr float kEps = 1e-9f;
constexpr int kPF = 8;
constexpr int kNC = kL / kPF;

#define DPP_ADD_F32(v, ctrl)                                                   \
    v += __int_as_float(__builtin_amdgcn_update_dpp(                           \
        0, __float_as_int(v), (ctrl), 0xF, 0xF, true))

__device__ __forceinline__ float rl(float v, int l) {
    return __int_as_float(__builtin_amdgcn_readlane(__float_as_int(v), l));
}
__device__ __forceinline__ float frcp(float x) { return __builtin_amdgcn_rcpf(x); }
__device__ __forceinline__ float frsq(float x) { return __builtin_amdgcn_rsqf(x); }

// Circular all-reduce within each row of 16: every lane ends with its row sum.
__device__ __forceinline__ float rowsum16(float v) {
    DPP_ADD_F32(v, 0x121);  // row_ror:1
    DPP_ADD_F32(v, 0x122);  // row_ror:2
    DPP_ADD_F32(v, 0x124);  // row_ror:4
    DPP_ADD_F32(v, 0x128);  // row_ror:8
    return v;
}

typedef unsigned u32x2v __attribute__((ext_vector_type(2)));

// Row-pair sum (proven in r10): uniform row-32 sum per 32-half.
__device__ __forceinline__ float pairsum16(float v) {
    u32x2v r = __builtin_amdgcn_permlane16_swap(__float_as_uint(v),
                                                __float_as_uint(v),
                                                false, false);
    return __uint_as_float(r[0]) + __uint_as_float(r[1]);
}

// Half-pair sum: out = v(lane) + v(lane^32), uniform across the wave.
__device__ __forceinline__ float pairsum32(float v) {
    u32x2v r = __builtin_amdgcn_permlane32_swap(__float_as_uint(v),
                                                __float_as_uint(v),
                                                false, false);
    return __uint_as_float(r[0]) + __uint_as_float(r[1]);
}

typedef const __attribute__((address_space(1))) float gfloat;
typedef __attribute__((address_space(3))) float lfloat;

// ---------- precompute meta[b,t][8] = {su, Gr, Gi, 0, xr0, xi0, xr1, xi1} ---
// su = lrW/(sum|u(t)|^2+eps); G = <conj u(t), u(t+1)> (state-independent!)
__global__ __launch_bounds__(256, 1) void pre_kernel(
    const float* __restrict__ u_r, const float* __restrict__ u_i,
    const float* __restrict__ x_r, const float* __restrict__ x_i,
    float* __restrict__ meta)
{
    const int lane = threadIdx.x & 63;
    const int idx = blockIdx.x * 4 + (threadIdx.x >> 6);   // flat b*L + t
    int nidx = idx + 1;
    nidx = nidx < kB * kL ? nidx : kB * kL - 1;            // clamp (G unused at tail)
    const float a  = u_r[(size_t)idx * 64 + lane];
    const float c  = u_i[(size_t)idx * 64 + lane];
    const float an = u_r[(size_t)nidx * 64 + lane];
    const float cn = u_i[(size_t)nidx * 64 + lane];
    float e  = fmaf(a, a, c * c);
    float gr = fmaf(a, an, c * cn);        // Re sum conj(u)*un
    float gi = fmaf(a, cn, -c * an);       // Im sum conj(u)*un
    e = rowsum16(e); gr = rowsum16(gr); gi = rowsum16(gi);
    e = pairsum16(e); gr = pairsum16(gr); gi = pairsum16(gi);
    e = pairsum32(e); gr = pairsum32(gr); gi = pairsum32(gi);
    if (lane == 0) {
        float4* m = (float4*)(meta + (size_t)idx * 8);
        m[0] = make_float4(kLrW * frcp(e + kEps), gr, gi, 0.0f);
        const float2 xr = *(const float2*)(x_r + (size_t)idx * 2);
        const float2 xi = *(const float2*)(x_i + (size_t)idx * 2);
        m[1] = make_float4(xr.x, xi.x, xr.y, xi.y);
    }
}

// ---------- main scan kernel ------------------------------------------------
// Serial cycle = f-path only: v(t) -> k,ef,H -> f -> psi -> sdp(t+1) -> tau(t+1)
// v(t+1) = look(t+1) + tau(t)*G(t,t+1)   [12 cy after v(t)]
// look(t+1) = <w(t), u(t+1)> reduced with a full body of slack.
__global__ __launch_bounds__(64, 1) void adf_kernel(
    const float* __restrict__ u_r, const float* __restrict__ u_i,
    const float* __restrict__ w0r_g, const float* __restrict__ w0i_g,
    const float* __restrict__ f0r_g, const float* __restrict__ f0i_g,
    const float* __restrict__ meta, float* __restrict__ out)
{
    __shared__ float lu[2][kPF][64];
    __shared__ float lq[2][kPF][64];
    __shared__ float lm[2][64];

    const int b = blockIdx.x;
    const int lane = threadIdx.x;
    const int half = lane >> 5;
    const int tap  = lane & 31;

    const int wbase = b * 128 + half * 64 + tap;
    float wAr = w0r_g[wbase],      wAi = w0i_g[wbase];
    float wBr = w0r_g[wbase + 32], wBi = w0i_g[wbase + 32];
    float fr = f0r_g[b * 2 + half];
    float fi = f0i_g[b * 2 + half];

    gfloat* gu = (gfloat*)u_r + (size_t)b * kL * 64 + lane;
    gfloat* gq = (gfloat*)u_i + (size_t)b * kL * 64 + lane;
    gfloat* gm = (gfloat*)meta + (size_t)b * kL * 8 + lane;
    float2* __restrict__ ob2 = (float2*)out + (size_t)b * kL * 2;

    auto stage = [&](int chunk) {   // 17 vmem ops
        const int par = chunk & 1;
#pragma unroll
        for (int s = 0; s < kPF; ++s) {
            __builtin_amdgcn_global_load_lds(gu + (size_t)(chunk * kPF + s) * 64,
                                             (lfloat*)&lu[par][s][0], 4, 0, 0);
            __builtin_amdgcn_global_load_lds(gq + (size_t)(chunk * kPF + s) * 64,
                                             (lfloat*)&lq[par][s][0], 4, 0, 0);
        }
        __builtin_amdgcn_global_load_lds(gm + (size_t)chunk * 64,
                                         (lfloat*)&lm[par][0], 4, 0, 0);
    };
    auto ldu = [&](int par, int s) { return *(const float2*)&lu[par][s][tap * 2]; };
    auto ldq = [&](int par, int s) { return *(const float2*)&lq[par][s][tap * 2]; };

    stage(0);
    stage(1);

    // prologue meta t=0,1 from global (one-time latency)
    const float* mg = meta + (size_t)b * kL * 8;
    const float4 m0a = *(const float4*)(mg);
    const float2 m0d = *(const float2*)(mg + 4 + half * 2);
    const float4 m1a = *(const float4*)(mg + 8);
    const float2 m1d = *(const float2*)(mg + 12 + half * 2);

    asm volatile("s_waitcnt vmcnt(0)" ::: "memory");   // chunks 0,1 resident

    float2 cu = ldu(0, 0), cq = ldq(0, 0);   // u(t)
    float2 nu = ldu(0, 1), nq = ldq(0, 1);   // u(t+1)
    float2 pu = ldu(0, 2), pq = ldq(0, 2);   // u(t+2)

    float suc = m0a.x, Gcr = m0a.y, Gci = m0a.z, dcr = m0d.x, dci = m0d.y;
    float sun = m1a.x, Gnr = m1a.y, Gni = m1a.z, dnr = m1d.x, dni = m1d.y;

    // sdp(0) = su(0)*d(0)*psi(f0)
    float sdpr, sdpi;
    {
        const float invf0 = frsq(fmaf(fr, fr, fi * fi));
        const float psr = fr * invf0, psm = -fi * invf0;
        sdpr = suc * fmaf(dcr, psr, -dci * psm);
        sdpi = suc * fmaf(dcr, psm,  dci * psr);
    }

    // v(0) = <w0,u(0)>; look(1) = <w0,u(1)>
    float vr, vi, lookr, looki;
    {
        float pr = wAr * cu.x;
        pr = fmaf(-wAi, cq.x, pr); pr = fmaf(wBr, cu.y, pr); pr = fmaf(-wBi, cq.y, pr);
        float pi = wAr * cq.x;
        pi = fmaf(wAi, cu.x, pi); pi = fmaf(wBr, cq.y, pi); pi = fmaf(wBi, cu.y, pi);
        pr = rowsum16(pr); pi = rowsum16(pi);
        vr = pairsum16(pr); vi = pairsum16(pi);
    }
    {
        float pr = wAr * nu.x;
        pr = fmaf(-wAi, nq.x, pr); pr = fmaf(wBr, nu.y, pr); pr = fmaf(-wBi, nq.y, pr);
        float pi = wAr * nq.x;
        pi = fmaf(wAi, nu.x, pi); pi = fmaf(wBr, nq.y, pi); pi = fmaf(wBi, nu.y, pi);
        pr = rowsum16(pr); pi = rowsum16(pi);
        lookr = pairsum16(pr); looki = pairsum16(pi);
    }

    float kR[kPF], kI[kPF];

    for (int c = 0; c < kNC; ++c) {
        const int par = c & 1;
#pragma unroll
        for (int s = 0; s < kPF; ++s) {
            // bodies 5..7 read next chunk's LDS: drain stage(c+1) (old, cheap)
            if (s == 5) asm volatile("s_waitcnt vmcnt(0)" ::: "memory");
            // ds reads: u(t+3), meta(t+2) -- 1-2 bodies of slack
            const int su3 = (s + 3) & 7; const int pu3 = (s < 5) ? par : par ^ 1;
            const float2 fu = ldu(pu3, su3), fq = ldq(pu3, su3);
            const int sm2 = (s + 2) & 7; const int pm2 = (s < 6) ? par : par ^ 1;
            const float4 mA = *(const float4*)&lm[pm2][sm2 * 8];
            const float2 mD = *(const float2*)&lm[pm2][sm2 * 8 + 4 + half * 2];

            // ---- 12-cy v chain: tau -> vNext (Gram fixup) ----
            const float taur = fmaf(-suc, vr, sdpr);
            const float taui = fmaf(-suc, vi, sdpi);
            const float vnr = fmaf(taur, Gcr, fmaf(-taui, Gci, lookr));
            const float vni = fmaf(taur, Gci, fmaf( taui, Gcr, looki));

            // ---- off-cycle: w update, lookahead partials + reduce ----
            wAr = fmaf(taur, cu.x, fmaf(taui, cq.x, wAr));
            wAi = fmaf(taui, cu.x, fmaf(-taur, cq.x, wAi));
            wBr = fmaf(taur, cu.y, fmaf(taui, cq.y, wBr));
            wBi = fmaf(taui, cu.y, fmaf(-taur, cq.y, wBi));
            float pr = wAr * pu.x;
            pr = fmaf(-wAi, pq.x, pr); pr = fmaf(wBr, pu.y, pr); pr = fmaf(-wBi, pq.y, pr);
            float pi = wAr * pq.x;
            pi = fmaf(wAi, pu.x, pi); pi = fmaf(wBr, pq.y, pi); pi = fmaf(wBi, pu.y, pi);
            pr = rowsum16(pr); pi = rowsum16(pi);
            const float nlookr = pairsum16(pr);
            const float nlooki = pairsum16(pi);

            // ---- serial f-path at v(t): k -> ef -> H -> f -> psi -> sdp(t+1)
            const float kr = fmaf(vr, fr, -vi * fi);
            const float ki = fmaf(vr, fi,  vi * fr);
            kR[s] = kr; kI[s] = ki;
            const float efr = dcr - kr, efi = dci - ki;
            const float mv2 = fmaf(vr, vr, vi * vi);
            const float ven = pairsum32(mv2) + kEps;
            const float nv = frcp(ven);                       // off-chain vs H
            const float Hr = fmaf(efi, vi, efr * vr);         // ef*conj(v)
            const float Hi = fmaf(-efr, vi, efi * vr);
            const float MH = fmaf(Hr, Hr, Hi * Hi);
            const float sc2 = fminf(nv, kGradMax * frsq(MH)); // clip folded, 1 trans
            const float scl = kLrF * sc2;
            fr = fmaf(scl, Hr, fr);                           // f -= lrF*gf
            fi = fmaf(scl, Hi, fi);
            const float iff = frsq(fmaf(fr, fr, fi * fi));
            const float psr2 = fr * iff, psm2 = -fi * iff;
            sdpr = sun * fmaf(dnr, psr2, -dni * psm2);
            sdpi = sun * fmaf(dnr, psm2,  dni * psr2);

            // ---- rotations ----
            vr = vnr; vi = vni;
            suc = sun; Gcr = Gnr; Gci = Gni; dcr = dnr; dci = dni;
            sun = mA.x; Gnr = mA.y; Gni = mA.z; dnr = mD.x; dni = mD.y;
            lookr = nlookr; looki = nlooki;
            cu = nu; cq = nq; nu = pu; nq = pq; pu = fu; pq = fq;
        }

        if (tap == 0) {
#pragma unroll
            for (int s = 0; s < kPF; ++s)
                ob2[(size_t)(c * kPF + s) * 2 + half] = make_float2(kR[s], kI[s]);
        }
        asm volatile("s_waitcnt lgkmcnt(0)" ::: "memory");
        stage((c + 2 < kNC) ? c + 2 : kNC - 1);
    }
}

// ---------- fallback (r7-style, 838 us) if ws too small ---------------------
__global__ __launch_bounds__(64, 1) void adf_fb(
    const float* __restrict__ u_r, const float* __restrict__ u_i,
    const float* __restrict__ x_r, const float* __restrict__ x_i,
    const float* __restrict__ w0r_g, const float* __restrict__ w0i_g,
    const float* __restrict__ f0r_g, const float* __restrict__ f0i_g,
    float* __restrict__ out)
{
    const int b = blockIdx.x;
    const int lane = threadIdx.x;
    const int half = lane >> 5;
    const int tap  = lane & 31;
    const bool lo  = (half == 0);

    const int wbase = b * 128 + half * 64 + tap;
    float wAr = w0r_g[wbase],      wAi = w0i_g[wbase];
    float wBr = w0r_g[wbase + 32], wBi = w0i_g[wbase + 32];

    float fr = f0r_g[b * 2 + half];
    float fi = f0i_g[b * 2 + half];
    const float invf0 = frsq(fmaf(fr, fr, fi * fi));
    float psr = fr * invf0, psm = -fi * invf0;

    const float2* __restrict__ ur2 = (const float2*)u_r + (size_t)b * kL * 32;
    const float2* __restrict__ ui2 = (const float2*)u_i + (size_t)b * kL * 32;
    const float2* __restrict__ xr2 = (const float2*)x_r + (size_t)b * kL;
    const float2* __restrict__ xi2 = (const float2*)x_i + (size_t)b * kL;
    float2* __restrict__ ob2 = (float2*)out + (size_t)b * kL * 2;

    float2 Au[kPF], Aq[kPF], AxR[kPF], AxI[kPF];
    float2 Bu[kPF], Bq[kPF], BxR[kPF], BxI[kPF];
    float suA[kPF], suB[kPF];
    float kR[kPF], kI[kPF];
    float sdpr = 0.0f, sdpi = 0.0f;

    auto loadChunk = [&](float2 (&u)[kPF], float2 (&q)[kPF],
                         float2 (&xR)[kPF], float2 (&xI)[kPF], int chunk) {
#pragma unroll
        for (int s = 0; s < kPF; ++s) {
            int t = chunk * kPF + s;
            t = t < kL ? t : kL - 1;
            u[s]  = ur2[(size_t)t * 32 + tap];
            q[s]  = ui2[(size_t)t * 32 + tap];
            xR[s] = xr2[t];
            xI[s] = xi2[t];
        }
        __builtin_amdgcn_sched_barrier(0);
    };

    auto calcSu = [&](float2 (&u)[kPF], float2 (&q)[kPF], float (&su)[kPF]) {
        float e[kPF];
#pragma unroll
        for (int s = 0; s < kPF; ++s) {
            float t0 = u[s].x * u[s].x;
            t0 = fmaf(u[s].y, u[s].y, t0);
            t0 = fmaf(q[s].x, q[s].x, t0);
            t0 = fmaf(q[s].y, q[s].y, t0);
            e[s] = t0;
        }
#pragma unroll
        for (int s = 0; s < kPF; ++s) { DPP_ADD_F32(e[s], 0x111); }
#pragma unroll
        for (int s = 0; s < kPF; ++s) { DPP_ADD_F32(e[s], 0x112); }
#pragma unroll
        for (int s = 0; s < kPF; ++s) { DPP_ADD_F32(e[s], 0x114); }
#pragma unroll
        for (int s = 0; s < kPF; ++s) { DPP_ADD_F32(e[s], 0x118); }
#pragma unroll
        for (int s = 0; s < kPF; ++s) { DPP_ADD_F32(e[s], 0x142); }
#pragma unroll
        for (int s = 0; s < kPF; ++s) su[s] = kLrW * frcp(rl(e[s], 31) + kEps);
    };

    auto body = [&](int s, float2 (&u)[kPF], float2 (&q)[kPF],
                    float2 (&xR)[kPF], float2 (&xI)[kPF], float (&su)[kPF],
                    bool first) {
        const float2 uc = u[s], qc = q[s];
        if (first) {
            const float dr0 = lo ? xR[0].x : xR[0].y;
            const float di0 = lo ? xI[0].x : xI[0].y;
            sdpr = su[0] * fmaf(dr0, psr, -di0 * psm);
            sdpi = su[0] * fmaf(dr0, psm,  di0 * psr);
        }
        float pr = wAr * uc.x;
        pr = fmaf(-wAi, qc.x, pr); pr = fmaf(wBr, uc.y, pr); pr = fmaf(-wBi, qc.y, pr);
        float pi = wAr * qc.x;
        pi = fmaf(wAi, uc.x, pi); pi = fmaf(wBr, qc.y, pi); pi = fmaf(wBi, uc.y, pi);
        DPP_ADD_F32(pr, 0x111); DPP_ADD_F32(pi, 0x111);
        DPP_ADD_F32(pr, 0x112); DPP_ADD_F32(pi, 0x112);
        DPP_ADD_F32(pr, 0x114); DPP_ADD_F32(pi, 0x114);
        DPP_ADD_F32(pr, 0x118); DPP_ADD_F32(pi, 0x118);
        DPP_ADD_F32(pr, 0x142); DPP_ADD_F32(pi, 0x142);
        const float v0r = rl(pr, 31), v1r = rl(pr, 63);
        const float v0i = rl(pi, 31), v1i = rl(pi, 63);
        const float vr = lo ? v0r : v1r;
        const float vi = lo ? v0i : v1i;

        const float sun = su[s];
        const float tr = fmaf(-sun, vr, sdpr);
        const float ti = fmaf(-sun, vi, sdpi);
        wAr = fmaf(tr, uc.x, fmaf(ti, qc.x, wAr));
        wAi = fmaf(ti, uc.x, fmaf(-tr, qc.x, wAi));
        wBr = fmaf(tr, uc.y, fmaf(ti, qc.y, wBr));
        wBi = fmaf(ti, uc.y, fmaf(-tr, qc.y, wBi));

        const float dr = lo ? xR[s].x : xR[s].y;
        const float di = lo ? xI[s].x : xI[s].y;
        const float kr = fmaf(vr, fr, -vi * fi);
        const float ki = fmaf(vr, fi,  vi * fr);
        kR[s] = kr; kI[s] = ki;
        const float efr = dr - kr, efi = di - ki;
        float ven = v0r * v0r;
        ven = fmaf(v0i, v0i, ven);
        ven = fmaf(v1r, v1r, ven);
        ven = fmaf(v1i, v1i, ven);
        const float nv = frcp(ven + kEps);
        float hr = efr * vr; hr = fmaf(efi, vi, hr);
        float hi = efi * vr; hi = fmaf(-efr, vi, hi);
        hr *= nv; hi *= nv;
        float mg = hr * hr; mg = fmaf(hi, hi, mg);
        const float sc = fminf(1.0f, kGradMax * frsq(mg));
        const float scl = kLrF * sc;
        fr = fmaf(scl, hr, fr);
        fi = fmaf(scl, hi, fi);
        const float invf = frsq(fmaf(fr, fr, fi * fi));
        psr = fr * invf; psm = -fi * invf;
        if (s + 1 < kPF) {
            const float dnr = lo ? xR[s + 1].x : xR[s + 1].y;
            const float dni = lo ? xI[s + 1].x : xI[s + 1].y;
            sdpr = su[s + 1] * fmaf(dnr, psr, -dni * psm);
            sdpi = su[s + 1] * fmaf(dnr, psm,  dni * psr);
        }
    };

    auto processChunk = [&](int tbase, float2 (&u)[kPF], float2 (&q)[kPF],
                            float2 (&xR)[kPF], float2 (&xI)[kPF], float (&su)[kPF]) {
#pragma unroll
        for (int s = 0; s < kPF; ++s)
            body(s, u, q, xR, xI, su, s == 0);
        if (tap == 0) {
#pragma unroll
            for (int s = 0; s < kPF; ++s)
                ob2[(size_t)(tbase + s) * 2 + half] = make_float2(kR[s], kI[s]);
        }
    };

    loadChunk(Au, Aq, AxR, AxI, 0);
    loadChunk(Bu, Bq, BxR, BxI, 1);
    calcSu(Au, Aq, suA);

    for (int c = 0; c < kNC; c += 2) {
        processChunk(c * kPF, Au, Aq, AxR, AxI, suA);
        loadChunk(Au, Aq, AxR, AxI, (c + 2 < kNC) ? c + 2 : kNC - 1);
        calcSu(Bu, Bq, suB);
        processChunk((c + 1) * kPF, Bu, Bq, BxR, BxI, suB);
        loadChunk(Bu, Bq, BxR, BxI, (c + 3 < kNC) ? c + 3 : kNC - 1);
        calcSu(Au, Aq, suA);
    }
}

} // namespace

extern "C" void kernel_launch(void* const* d_in, const int* in_sizes, int n_in,
                              void* d_out, int out_size, void* d_ws, size_t ws_size,
                              hipStream_t stream) {
    const float* u_r  = (const float*)d_in[0];
    const float* u_i  = (const float*)d_in[1];
    const float* x_r  = (const float*)d_in[2];
    const float* x_i  = (const float*)d_in[3];
    const float* w0_r = (const float*)d_in[4];
    const float* w0_i = (const float*)d_in[5];
    const float* f0_r = (const float*)d_in[6];
    const float* f0_i = (const float*)d_in[7];
    float* out = (float*)d_out;

    const size_t need = (size_t)kB * kL * 8 * sizeof(float);   // 8 MB meta
    if (ws_size >= need) {
        float* meta = (float*)d_ws;
        dim3 pgrid(kB * kL / 4);
        pre_kernel<<<pgrid, 256, 0, stream>>>(u_r, u_i, x_r, x_i, meta);
        adf_kernel<<<dim3(kB), dim3(64), 0, stream>>>(
            u_r, u_i, w0_r, w0_i, f0_r, f0_i, meta, out);
    } else {
        adf_fb<<<dim3(kB), dim3(64), 0, stream>>>(
            u_r, u_i, x_r, x_i, w0_r, w0_i, f0_r, f0_i, out);
    }
}